// Round 2
// 175.479 us; speedup vs baseline: 1.0105x; 1.0105x over previous
//
#include <hip/hip_runtime.h>
#include <hip/hip_bf16.h>

typedef __bf16 bf16x8 __attribute__((ext_vector_type(8)));
typedef float f32x4 __attribute__((ext_vector_type(4)));
typedef float f32x16 __attribute__((ext_vector_type(16)));
typedef int int4v __attribute__((ext_vector_type(4)));
typedef unsigned int uint4v __attribute__((ext_vector_type(4)));
typedef unsigned short u16x8 __attribute__((ext_vector_type(8)));

#define N_NODES 8192
#define D_FEAT 128

// ---------------------------------------------------------------------------
// Bit->bf16 pair unpack: byte (8 adjacency bits) -> bf16x8 of {0.0, 1.0}.
// All muls fit u24 (compiler emits v_mul_u32_u24, full rate).
__device__ __forceinline__ bf16x8 unpack_byte(unsigned dword, int sh) {
  unsigned P = ((dword >> sh) & 0xFFu) * 0x8001u;
  uint4v c;
  c[0] = (P & 0x10001u) * 0x3F80u;
  c[1] = ((P >> 2) & 0x10001u) * 0x3F80u;
  c[2] = ((P >> 4) & 0x10001u) * 0x3F80u;
  c[3] = ((P >> 6) & 0x10001u) * 0x3F80u;
  return __builtin_bit_cast(bf16x8, c);
}

// ---------------------------------------------------------------------------
// Bpk fragment build for the 32x32x16 GEMM.
// Fragment f = kk*256 + ng*64 + l holds, at element e:
//   F[node sigma(kk*16 + (l>>5)*8 + e)][ng*32 + (l&31)]
// where sigma compensates the ballot-pack bit permutation:
//   sigma(p) = 256*(p>>8) + 32*((p>>3)&7) + 4*(p&7) + ((p>>6)&3)
__device__ __forceinline__ void bpk32_store(const float* __restrict__ src,
                                            unsigned short* __restrict__ Bpk,
                                            int W) {
  const int kk = W >> 8;            // 0..511  (K-steps of 16)
  const int ng = (W >> 6) & 3;      // 0..3    (32-col groups)
  const int l = W & 63;
  const int d = ng * 32 + (l & 31);
  const int p0 = kk * 16 + (l >> 5) * 8;
  const int n0 = (p0 >> 8) * 256 + ((p0 >> 3) & 7) * 32 + ((p0 >> 6) & 3);
  u16x8 pk;
#pragma unroll
  for (int e = 0; e < 8; ++e) {
    __bf16 v = (__bf16)src[(long)(n0 + 4 * e) * D_FEAT + d];
    pk[e] = __builtin_bit_cast(unsigned short, v);
  }
  *(u16x8*)(Bpk + (long)W * 8) = pk;
}

// ---------------------------------------------------------------------------
// K1: pure-streaming mega-pack. Packs BOTH layers' adjacency rows
// (row in [0,16384)) into bits64 + deg via coalesced int4 loads + ballots,
// and builds layer-1 Bpk (first 512 blocks). No GEMM competes for issue
// slots -> the 512 MiB adjacency read should run at ~full HBM BW.
__global__ __launch_bounds__(256) void pack_all_kernel(
    const int* __restrict__ adj, unsigned long long* __restrict__ bits64,
    int* __restrict__ deg, const float* __restrict__ fsrc,
    unsigned short* __restrict__ Bpk) {
  const int bx = blockIdx.x;
  const int t = threadIdx.x;

  if (bx < 512) {  // layer-1 Bpk build (reads only the input features)
    bpk32_store(fsrc, Bpk, bx * 256 + t);
    return;
  }

  const int row = bx - 512;  // 0..16383 across both layers
  const int w = t >> 6;
  const int lane = t & 63;
  const int4v* p = (const int4v*)(adj + ((long)row << 13));
  int4v v[8];
#pragma unroll
  for (int j = 0; j < 8; ++j) v[j] = p[j * 256 + t];

  unsigned long long* brow = bits64 + ((long)row << 7);
  int cnt = 0;
#pragma unroll
  for (int j = 0; j < 8; ++j) {
    unsigned long long b0 = __ballot(v[j][0] != 0);
    unsigned long long b1 = __ballot(v[j][1] != 0);
    unsigned long long b2 = __ballot(v[j][2] != 0);
    unsigned long long b3 = __ballot(v[j][3] != 0);
    cnt += __popcll(b0) + __popcll(b1) + __popcll(b2) + __popcll(b3);
    unsigned long long bsel = b0;
    if (lane == 1) bsel = b1;
    if (lane == 2) bsel = b2;
    if (lane == 3) bsel = b3;
    if (lane < 4) brow[16 * j + 4 * w + lane] = bsel;
  }
  __shared__ int red[4];
  if (lane == 0) red[w] = cnt;
  __syncthreads();
  if (t == 0) deg[row] = red[0] + red[1] + red[2] + red[3];
}

// ---------------------------------------------------------------------------
// K3: rebuild Bpk from layer-1 output.
__global__ __launch_bounds__(256) void bpk_build32_kernel(
    const float* __restrict__ src, unsigned short* __restrict__ Bpk) {
  bpk32_store(src, Bpk, blockIdx.x * 256 + threadIdx.x);
}

// ---------------------------------------------------------------------------
// Layer body, 32x32x16 MFMA version.
// Block = 64 rows x 64 cols, 512 thr = 8 waves = 2 col-groups(ntl) x 4 K-quarters(kh).
// Each wave: 2 m-tiles of 32 rows sharing each B fragment (keeps B L2 traffic
// at 256 MiB/layer), 16 kg-iters x 8 K-steps. Unpack cost per MAC is HALF the
// 16x16x32 version (same 14-op unpack feeds 16384 MACs).
// A layout: lane l holds row l&31, K-bits (l>>5)*8..+7 of each 16-bit K-step,
// LSB-first linear bit positions in bits32 (sigma-compensated in Bpk).
// C/D layout (m101): col=l&31, row=(r&3)+8*(r>>2)+4*(l>>5).
__device__ __forceinline__ void layer_body32(
    int rowblk, int nthalf,
    const unsigned* __restrict__ bits, const int* __restrict__ deg,
    const unsigned short* __restrict__ Bpk,
    const float* fin, float* fout,
    f32x4 (*red)[2][2][4][64]) {
  const int tid = threadIdx.x;
  const int lane = tid & 63;
  const int w = tid >> 6;        // 0..7
  const int ntl = w & 1;         // col group within block
  const int kh = w >> 1;         // 0..3  K-quarter (2048 bits)
  const int l31 = lane & 31;
  const int lh = lane >> 5;      // 0/1
  const int m0 = rowblk * 64;
  const int ng = nthalf * 2 + ntl;  // 0..3 global 32-col group
  const int shA = lh * 8;
  const int shB = shA + 16;

  // A: row stride 1 KiB (256 u32); K-quarter = 16 uint4.
  const uint4v* ap0 = (const uint4v*)(bits + ((long)(m0 + l31) << 8)) + kh * 16;
  const uint4v* ap1 =
      (const uint4v*)(bits + ((long)(m0 + 32 + l31) << 8)) + kh * 16;
  // B: fragment index f = kk*256 + ng*64 + lane; kk = kh*128 + kg*8 + s.
  const bf16x8* bp = (const bf16x8*)Bpk + ((long)kh << 15) + ng * 64 + lane;

  f32x16 acc0 = {0.f, 0.f, 0.f, 0.f, 0.f, 0.f, 0.f, 0.f,
                 0.f, 0.f, 0.f, 0.f, 0.f, 0.f, 0.f, 0.f};
  f32x16 acc1 = {0.f, 0.f, 0.f, 0.f, 0.f, 0.f, 0.f, 0.f,
                 0.f, 0.f, 0.f, 0.f, 0.f, 0.f, 0.f, 0.f};

#pragma unroll 2
  for (int kg = 0; kg < 16; ++kg) {
    uint4v a0 = ap0[kg];
    uint4v a1 = ap1[kg];
#pragma unroll
    for (int s = 0; s < 8; ++s) {
      bf16x8 bv = *bp;
      bp += 256;
      const int sh = (s & 1) ? shB : shA;
      acc0 = __builtin_amdgcn_mfma_f32_32x32x16_bf16(
          unpack_byte(a0[s >> 1], sh), bv, acc0, 0, 0, 0);
      acc1 = __builtin_amdgcn_mfma_f32_32x32x16_bf16(
          unpack_byte(a1[s >> 1], sh), bv, acc1, 0, 0, 0);
    }
  }

  // Split-K combine: quarters 1..3 store (lane-contiguous f32x4 chunks,
  // conflict-free b128 pattern), quarter 0 accumulates.
  // NOTE: __builtin_shufflevector needs literal-constant indices -> macro.
  if (kh) {
#define STORE_CHUNK(c)                                                       \
  red[kh - 1][ntl][0][c][lane] = __builtin_shufflevector(                    \
      acc0, acc0, 4 * (c), 4 * (c) + 1, 4 * (c) + 2, 4 * (c) + 3);           \
  red[kh - 1][ntl][1][c][lane] = __builtin_shufflevector(                    \
      acc1, acc1, 4 * (c), 4 * (c) + 1, 4 * (c) + 2, 4 * (c) + 3);
    STORE_CHUNK(0)
    STORE_CHUNK(1)
    STORE_CHUNK(2)
    STORE_CHUNK(3)
#undef STORE_CHUNK
  }
  __syncthreads();
  if (kh) return;

#pragma unroll
  for (int q = 0; q < 3; ++q) {
#pragma unroll
    for (int c = 0; c < 4; ++c) {
      f32x4 r0 = red[q][ntl][0][c][lane];
      f32x4 r1 = red[q][ntl][1][c][lane];
#pragma unroll
      for (int k = 0; k < 4; ++k) {
        acc0[4 * c + k] += r0[k];
        acc1[4 * c + k] += r1[k];
      }
    }
  }

  // Epilogue: col = ng*32 + l31, row = m0 + mt*32 + (r&3) + 8*(r>>2) + 4*lh.
#pragma unroll
  for (int mt = 0; mt < 2; ++mt) {
#pragma unroll
    for (int r = 0; r < 16; ++r) {
      const int row = m0 + mt * 32 + (r & 3) + 8 * (r >> 2) + 4 * lh;
      const int dg = deg[row];
      const float a = mt ? acc1[r] : acc0[r];
      const long off = (long)row * D_FEAT + ng * 32 + l31;
      fout[off] = dg > 0 ? a * (1.0f / (float)dg) : fin[off];
    }
  }
}

// ---------------------------------------------------------------------------
// K2/K4: standalone layer GEMM. grid 256 = 128 rowblks x 2 col-halves.
__global__ __launch_bounds__(512, 2) void layer32_kernel(
    const unsigned* __restrict__ bits, const int* __restrict__ deg,
    const unsigned short* __restrict__ Bpk, const float* fin, float* fout) {
  __shared__ __align__(16) f32x4 red[3][2][2][4][64];  // 48 KiB
  layer_body32(blockIdx.x >> 1, blockIdx.x & 1, bits, deg, Bpk, fin, fout,
               red);
}

// ---------------------------------------------------------------------------
// Fallback path (round-1 verified), used only if ws too small.
__global__ __launch_bounds__(256) void transpose_cast_kernel(
    const float* __restrict__ src, unsigned short* __restrict__ dst) {
  __shared__ float tile[64][129];
  const int t = threadIdx.x;
  const int nbase = blockIdx.x * 64;
#pragma unroll
  for (int i = 0; i < 32; ++i) {
    int idx = t + i * 256;
    int nl = idx >> 7;
    int d = idx & 127;
    tile[nl][d] = src[(long)(nbase + nl) * D_FEAT + d];
  }
  __syncthreads();
#pragma unroll
  for (int i = 0; i < 32; ++i) {
    int idx = t + i * 256;
    int d = idx >> 6;
    int nl = idx & 63;
    __bf16 b = (__bf16)tile[nl][d];
    dst[(long)d * N_NODES + nbase + nl] = __builtin_bit_cast(unsigned short, b);
  }
}

__global__ __launch_bounds__(512) void layer_kernel_direct(
    const int* __restrict__ adj, const unsigned short* __restrict__ BT,
    const float* __restrict__ fin, float* __restrict__ fout) {
  const int tid = threadIdx.x;
  const int lane = tid & 63;
  const int w = tid >> 6;
  const int m0 = blockIdx.x * 32 + (w >> 2) * 16;
  const int n0 = (w & 3) * 32;
  const int lr = lane & 15;
  const int kc = lane >> 4;

  const int4v* ap = (const int4v*)(adj + (long)(m0 + lr) * N_NODES + kc * 8);
  const bf16x8* bp0 = (const bf16x8*)(BT + (long)(n0 + lr) * N_NODES + kc * 8);
  const bf16x8* bp1 =
      (const bf16x8*)(BT + (long)(n0 + 16 + lr) * N_NODES + kc * 8);

  f32x4 acc0 = {0.f, 0.f, 0.f, 0.f};
  f32x4 acc1 = {0.f, 0.f, 0.f, 0.f};
  int degv = 0;

#pragma unroll 4
  for (int k = 0; k < N_NODES; k += 32) {
    int4v alo = ap[0];
    int4v ahi = ap[1];
    bf16x8 b0 = bp0[0];
    bf16x8 b1 = bp1[0];
    ap += 8;
    bp0 += 4;
    bp1 += 4;
    unsigned short u[8];
    u[0] = alo[0] ? 0x3F80 : 0;
    u[1] = alo[1] ? 0x3F80 : 0;
    u[2] = alo[2] ? 0x3F80 : 0;
    u[3] = alo[3] ? 0x3F80 : 0;
    u[4] = ahi[0] ? 0x3F80 : 0;
    u[5] = ahi[1] ? 0x3F80 : 0;
    u[6] = ahi[2] ? 0x3F80 : 0;
    u[7] = ahi[3] ? 0x3F80 : 0;
    degv += alo[0] + alo[1] + alo[2] + alo[3] + ahi[0] + ahi[1] + ahi[2] +
            ahi[3];
    bf16x8 a;
    memcpy(&a, u, 16);
    acc0 = __builtin_amdgcn_mfma_f32_16x16x32_bf16(a, b0, acc0, 0, 0, 0);
    acc1 = __builtin_amdgcn_mfma_f32_16x16x32_bf16(a, b1, acc1, 0, 0, 0);
  }

  degv += __shfl_xor(degv, 16);
  degv += __shfl_xor(degv, 32);
  int dgv[4];
#pragma unroll
  for (int j = 0; j < 4; ++j) dgv[j] = __shfl(degv, kc * 4 + j);

#pragma unroll
  for (int t = 0; t < 2; ++t) {
    const f32x4 acc = t ? acc1 : acc0;
    const int col = n0 + t * 16 + lr;
#pragma unroll
    for (int j = 0; j < 4; ++j) {
      const long off = (long)(m0 + kc * 4 + j) * D_FEAT + col;
      fout[off] = dgv[j] > 0 ? acc[j] * (1.0f / (float)dgv[j]) : fin[off];
    }
  }
}

// ---------------------------------------------------------------------------
extern "C" void kernel_launch(void* const* d_in, const int* in_sizes, int n_in,
                              void* d_out, int out_size, void* d_ws,
                              size_t ws_size, hipStream_t stream) {
  const float* features = (const float*)d_in[0];
  const int* adj = (const int*)d_in[1];
  float* out = (float*)d_out;
  const long NN = (long)N_NODES * N_NODES;

  const size_t BITS_BYTES = 2ul * N_NODES * 128 * 8;      // 16 MiB
  const size_t BPK_BYTES = (size_t)D_FEAT * N_NODES * 2;  // 2 MiB
  const size_t NEED = BITS_BYTES + 65536 + BPK_BYTES;

  if (ws_size >= NEED) {
    unsigned long long* bits64 = (unsigned long long*)d_ws;
    int* degw = (int*)((char*)d_ws + BITS_BYTES);
    unsigned short* Bpk = (unsigned short*)((char*)d_ws + BITS_BYTES + 65536);
    const unsigned* bits32 = (const unsigned*)d_ws;

    // K1: pure streaming — pack both layers' adjacency + build layer-1 Bpk.
    pack_all_kernel<<<2 * N_NODES + 512, 256, 0, stream>>>(adj, bits64, degw,
                                                           features, Bpk);
    // K2: layer-1 GEMM (32x32x16 MFMA), full machine.
    layer32_kernel<<<256, 512, 0, stream>>>(bits32, degw, Bpk, features, out);
    // K3: rebuild Bpk from layer-1 output.
    bpk_build32_kernel<<<512, 256, 0, stream>>>(out, Bpk);
    // K4: layer-2 GEMM.
    layer32_kernel<<<256, 512, 0, stream>>>(bits32 + (size_t)N_NODES * 256,
                                            degw + N_NODES, Bpk, out, out);
  } else {
    // Fallback: round-1 verified path (needs only 2 MiB ws)
    unsigned short* BTw = (unsigned short*)d_ws;
    transpose_cast_kernel<<<N_NODES / 64, 256, 0, stream>>>(features, BTw);
    layer_kernel_direct<<<N_NODES / 32, 512, 0, stream>>>(adj, BTw, features,
                                                          out);
    transpose_cast_kernel<<<N_NODES / 64, 256, 0, stream>>>(out, BTw);
    layer_kernel_direct<<<N_NODES / 32, 512, 0, stream>>>(adj + NN, BTw, out,
                                                          out);
  }
}